// Round 4
// baseline (132.990 us; speedup 1.0000x reference)
//
#include <hip/hip_runtime.h>

// Problem constants (from reference setup_inputs)
#define BB 4
#define CC 12
#define DD 8
#define HG 16
#define WG 16
#define HH 1024
#define WW 1024

// Native 4-float vector (clang ext vector) — legal operand for
// __builtin_nontemporal_load/store.
typedef float vf4 __attribute__((ext_vector_type(4)));

// LDS slab layout per row: S[x*XSTRIDE + z*CC + c], y-interpolation pre-folded.
// XSTRIDE = 8*12 + 8 pad floats = 104 -> cells stay 16B-aligned and
// bank = (8x + 12z + c) % 32 spreads the guide-random z across banks.
#define XSTRIDE 104
#define ROWS 2   // rows per block; grid = 2048 blocks = 8 blocks/CU supply.
                 // Even h0 never straddles an fy band (bands flip at
                 // h == 32 mod 64).

// ROWS=2 alone was neutral: residency was VGPR-capped at 4 waves/SIMD, so
// extra grid supply couldn't raise occupancy. Force <=84 VGPR -> 6 waves/SIMD
// (6 blocks/CU; LDS 6*13.3 KB = 80 KB fits).
__global__ __launch_bounds__(256, 6) void slice_apply(
    const float* __restrict__ grid,   // [B,C,D,HG,WG]
    const float* __restrict__ guide,  // [B,H,W]
    const float* __restrict__ img,    // [B,3,H,W]
    float* __restrict__ out)          // [B,3,H,W]
{
    __shared__ float S[ROWS * WG * XSTRIDE];  // 2 * 6656 B = 13312 B

    const int blk = blockIdx.x;
    const int b  = blk >> 9;                 // HH/ROWS = 512 row-groups per batch
    const int h0 = (blk & 511) * ROWS;

    // y-cell pair shared by all ROWS rows of this block
    const float gy0 = (h0 + 0.5f) * ((float)HG / (float)HH);
    const float fy  = floorf(gy0 - 0.5f);
    const int   iy0 = max(0, min(HG - 1, (int)fy));
    const int   iy1 = max(0, min(HG - 1, (int)fy + 1));

    float wy1r[ROWS];
    #pragma unroll
    for (int r = 0; r < ROWS; ++r) {
        const float gy = (h0 + r + 0.5f) * ((float)HG / (float)HH);
        wy1r[r] = gy - 0.5f - fy;           // ty in [0,1)
    }

    // Stage: load the two raw y-slices once, fold into ROWS per-row slabs.
    // 1536 cells; flat index ordered (c,z,x) so consecutive threads read
    // consecutive x (coalesced 64B segments).
    for (int j = threadIdx.x; j < CC * DD * WG; j += 256) {
        const int x = j & 15;
        const int z = (j >> 4) & 7;
        const int c = j >> 7;
        const size_t base = ((size_t)(b * CC + c) * DD + z) * (HG * WG);
        const float v0 = grid[base + iy0 * WG + x];
        const float v1 = grid[base + iy1 * WG + x];
        const int so = x * XSTRIDE + z * CC + c;
        #pragma unroll
        for (int r = 0; r < ROWS; ++r) {
            const float ty = wy1r[r];
            S[r * (WG * XSTRIDE) + so] = v0 + ty * (v1 - v0);
        }
    }
    __syncthreads();

    const int w0 = threadIdx.x * 4;

    // x cell pair is uniform across the 4 pixels of this thread
    const float scale = (float)WG / (float)WW;       // 1/64
    const float gx0 = (w0 + 0.5f) * scale;
    const float fx  = floorf(gx0 - 0.5f);
    const float tx0 = gx0 - 0.5f - fx;
    const int   ix0 = max(0, min(WG - 1, (int)fx));
    const int   ix1 = max(0, min(WG - 1, (int)fx + 1));

    #pragma unroll
    for (int r = 0; r < ROWS; ++r) {
        const int h = h0 + r;
        const float* Sr  = S + r * (WG * XSTRIDE);
        const float* Sx0 = Sr + ix0 * XSTRIDE;
        const float* Sx1 = Sr + ix1 * XSTRIDE;

        const size_t pix = ((size_t)b * HH + h) * WW + w0;
        const vf4 g4 = *reinterpret_cast<const vf4*>(guide + pix);
        const float* ib = img + (((size_t)b * 3) * HH + h) * WW + w0;
        const vf4 i0 = __builtin_nontemporal_load(reinterpret_cast<const vf4*>(ib));
        const vf4 i1 = __builtin_nontemporal_load(reinterpret_cast<const vf4*>(ib + (size_t)HH * WW));
        const vf4 i2 = __builtin_nontemporal_load(reinterpret_cast<const vf4*>(ib + (size_t)2 * HH * WW));

        vf4 o0, o1, o2;

        #pragma unroll
        for (int p = 0; p < 4; ++p) {
            const float tx  = tx0 + (float)p * scale;
            const float wx0 = 1.0f - tx, wx1 = tx;

            const float gv = g4[p];
            const float gz  = gv * (float)DD;
            const float fz  = floorf(gz - 0.5f);
            const float tz  = gz - 0.5f - fz;
            const int   iz0 = max(0, min(DD - 1, (int)fz));
            const int   iz1 = max(0, min(DD - 1, (int)fz + 1));
            const float wz0 = 1.0f - tz, wz1 = tz;

            const float w00 = wz0 * wx0, w01 = wz0 * wx1;
            const float w10 = wz1 * wx0, w11 = wz1 * wx1;

            float acc[12];
            #pragma unroll
            for (int k = 0; k < 12; ++k) acc[k] = 0.0f;

            auto accum = [&](const float* P, float w) {
                const vf4 a = *reinterpret_cast<const vf4*>(P);
                const vf4 e = *reinterpret_cast<const vf4*>(P + 4);
                const vf4 f = *reinterpret_cast<const vf4*>(P + 8);
                #pragma unroll
                for (int k = 0; k < 4; ++k) {
                    acc[k]     += w * a[k];
                    acc[4 + k] += w * e[k];
                    acc[8 + k] += w * f[k];
                }
            };
            accum(Sx0 + iz0 * CC, w00);
            accum(Sx1 + iz0 * CC, w01);
            accum(Sx0 + iz1 * CC, w10);
            accum(Sx1 + iz1 * CC, w11);

            const float im0 = i0[p];
            const float im1 = i1[p];
            const float im2 = i2[p];

            o0[p] = acc[0] * im0 + acc[1] * im1 + acc[2]  * im2 + acc[3];
            o1[p] = acc[4] * im0 + acc[5] * im1 + acc[6]  * im2 + acc[7];
            o2[p] = acc[8] * im0 + acc[9] * im1 + acc[10] * im2 + acc[11];
        }

        float* ob = out + (((size_t)b * 3) * HH + h) * WW + w0;
        __builtin_nontemporal_store(o0, reinterpret_cast<vf4*>(ob));
        __builtin_nontemporal_store(o1, reinterpret_cast<vf4*>(ob + (size_t)HH * WW));
        __builtin_nontemporal_store(o2, reinterpret_cast<vf4*>(ob + (size_t)2 * HH * WW));
    }
}

extern "C" void kernel_launch(void* const* d_in, const int* in_sizes, int n_in,
                              void* d_out, int out_size, void* d_ws, size_t ws_size,
                              hipStream_t stream) {
    const float* grid  = (const float*)d_in[0];
    const float* guide = (const float*)d_in[1];
    const float* image = (const float*)d_in[2];
    float* out = (float*)d_out;

    const int nblocks = BB * HH / ROWS;  // 2048 blocks, 2 rows each
    slice_apply<<<nblocks, 256, 0, stream>>>(grid, guide, image, out);
}

// Round 5
// 120.206 us; speedup vs baseline: 1.1063x; 1.1063x over previous
//
#include <hip/hip_runtime.h>

// Problem constants (from reference setup_inputs)
#define BB 4
#define CC 12
#define DD 8
#define HG 16
#define WG 16
#define HH 1024
#define WW 1024

// Native 4-float vector (clang ext vector) — legal operand for
// __builtin_nontemporal_load/store.
typedef float vf4 __attribute__((ext_vector_type(4)));

// LDS slab layout per row: S[x*XSTRIDE + z*CC + c], y-interpolation pre-folded.
// XSTRIDE = 8*12 + 8 pad floats = 104 -> cells stay 16B-aligned and
// bank = (8x + 12z + c) % 32 spreads the guide-random z across banks.
#define XSTRIDE 104
#define ROWS 2   // grid = 2048 blocks. Even h0 never straddles an fy band.
#define NSTG 6   // CC*DD*WG / 256 staging cells per thread

// NOTE: no min-waves clause. (256,6) forced VGPR=40 and the allocator
// serialized the loads (round-4: 43.7 us, occupancy still only 37% -> occupancy
// was never the binding constraint). The binding constraint is exposed global
// latency: __syncthreads() is a fence, so pixel loads placed after it cannot be
// hoisted by the compiler. Hoist them manually above the barrier instead.
__global__ __launch_bounds__(256) void slice_apply(
    const float* __restrict__ grid,   // [B,C,D,HG,WG]
    const float* __restrict__ guide,  // [B,H,W]
    const float* __restrict__ img,    // [B,3,H,W]
    float* __restrict__ out)          // [B,3,H,W]
{
    __shared__ float S[ROWS * WG * XSTRIDE];  // 2 * 6656 B = 13312 B

    const int blk = blockIdx.x;
    const int b  = blk >> 9;                 // HH/ROWS = 512 row-groups per batch
    const int h0 = (blk & 511) * ROWS;

    // y-cell pair shared by all ROWS rows of this block
    const float gy0 = (h0 + 0.5f) * ((float)HG / (float)HH);
    const float fy  = floorf(gy0 - 0.5f);
    const int   iy0 = max(0, min(HG - 1, (int)fy));
    const int   iy1 = max(0, min(HG - 1, (int)fy + 1));

    float wy1r[ROWS];
    #pragma unroll
    for (int r = 0; r < ROWS; ++r) {
        const float gy = (h0 + r + 0.5f) * ((float)HG / (float)HH);
        wy1r[r] = gy - 0.5f - fy;           // ty in [0,1)
    }

    // ---- Issue the block's 12 grid loads first (oldest in the vmem queue;
    // L2-resident after the first touch). Flat index ordered (c,z,x) so
    // consecutive threads read consecutive x (coalesced 64B segments).
    float v0[NSTG], v1[NSTG];
    int   so[NSTG];
    #pragma unroll
    for (int t = 0; t < NSTG; ++t) {
        const int j = (int)threadIdx.x + t * 256;
        const int x = j & 15;
        const int z = (j >> 4) & 7;
        const int c = j >> 7;
        const size_t base = ((size_t)(b * CC + c) * DD + z) * (HG * WG);
        v0[t] = grid[base + iy0 * WG + x];
        v1[t] = grid[base + iy1 * WG + x];
        so[t] = x * XSTRIDE + z * CC + c;
    }

    // ---- Issue all 8 guide/image vector loads for the 2 rows BEFORE the
    // barrier (the barrier's fence semantics stop the compiler from hoisting
    // them itself). Their ~900-cycle latency drains under the staging fold +
    // barrier wait. Only 8 vf4 = 32 VGPRs of pixel state (vs 64 in the failed
    // ROWS=4 version), and no launch-bounds cap fighting the allocator.
    const int w0 = (int)threadIdx.x * 4;
    vf4 g4[ROWS], i0[ROWS], i1[ROWS], i2[ROWS];
    #pragma unroll
    for (int r = 0; r < ROWS; ++r) {
        const size_t pix = ((size_t)b * HH + (h0 + r)) * WW + w0;
        g4[r] = *reinterpret_cast<const vf4*>(guide + pix);
        const float* ib = img + (((size_t)b * 3) * HH + (h0 + r)) * WW + w0;
        i0[r] = __builtin_nontemporal_load(reinterpret_cast<const vf4*>(ib));
        i1[r] = __builtin_nontemporal_load(reinterpret_cast<const vf4*>(ib + (size_t)HH * WW));
        i2[r] = __builtin_nontemporal_load(reinterpret_cast<const vf4*>(ib + (size_t)2 * HH * WW));
    }

    // ---- Fold the y-lerp into ROWS per-row slabs (waits only on the 12 grid
    // loads; the 8 pixel loads stay in flight across the barrier).
    #pragma unroll
    for (int t = 0; t < NSTG; ++t) {
        const float d = v1[t] - v0[t];
        #pragma unroll
        for (int r = 0; r < ROWS; ++r) {
            S[r * (WG * XSTRIDE) + so[t]] = v0[t] + wy1r[r] * d;
        }
    }
    __syncthreads();

    // x cell pair is uniform across the 4 pixels of this thread
    const float scale = (float)WG / (float)WW;       // 1/64
    const float gx0 = (w0 + 0.5f) * scale;
    const float fx  = floorf(gx0 - 0.5f);
    const float tx0 = gx0 - 0.5f - fx;
    const int   ix0 = max(0, min(WG - 1, (int)fx));
    const int   ix1 = max(0, min(WG - 1, (int)fx + 1));

    #pragma unroll
    for (int r = 0; r < ROWS; ++r) {
        const int h = h0 + r;
        const float* Sr  = S + r * (WG * XSTRIDE);
        const float* Sx0 = Sr + ix0 * XSTRIDE;
        const float* Sx1 = Sr + ix1 * XSTRIDE;

        vf4 o0, o1, o2;

        #pragma unroll
        for (int p = 0; p < 4; ++p) {
            const float tx  = tx0 + (float)p * scale;
            const float wx0 = 1.0f - tx, wx1 = tx;

            const float gv = g4[r][p];
            const float gz  = gv * (float)DD;
            const float fz  = floorf(gz - 0.5f);
            const float tz  = gz - 0.5f - fz;
            const int   iz0 = max(0, min(DD - 1, (int)fz));
            const int   iz1 = max(0, min(DD - 1, (int)fz + 1));
            const float wz0 = 1.0f - tz, wz1 = tz;

            const float w00 = wz0 * wx0, w01 = wz0 * wx1;
            const float w10 = wz1 * wx0, w11 = wz1 * wx1;

            float acc[12];
            #pragma unroll
            for (int k = 0; k < 12; ++k) acc[k] = 0.0f;

            auto accum = [&](const float* P, float w) {
                const vf4 a = *reinterpret_cast<const vf4*>(P);
                const vf4 e = *reinterpret_cast<const vf4*>(P + 4);
                const vf4 f = *reinterpret_cast<const vf4*>(P + 8);
                #pragma unroll
                for (int k = 0; k < 4; ++k) {
                    acc[k]     += w * a[k];
                    acc[4 + k] += w * e[k];
                    acc[8 + k] += w * f[k];
                }
            };
            accum(Sx0 + iz0 * CC, w00);
            accum(Sx1 + iz0 * CC, w01);
            accum(Sx0 + iz1 * CC, w10);
            accum(Sx1 + iz1 * CC, w11);

            const float im0 = i0[r][p];
            const float im1 = i1[r][p];
            const float im2 = i2[r][p];

            o0[p] = acc[0] * im0 + acc[1] * im1 + acc[2]  * im2 + acc[3];
            o1[p] = acc[4] * im0 + acc[5] * im1 + acc[6]  * im2 + acc[7];
            o2[p] = acc[8] * im0 + acc[9] * im1 + acc[10] * im2 + acc[11];
        }

        float* ob = out + (((size_t)b * 3) * HH + h) * WW + w0;
        __builtin_nontemporal_store(o0, reinterpret_cast<vf4*>(ob));
        __builtin_nontemporal_store(o1, reinterpret_cast<vf4*>(ob + (size_t)HH * WW));
        __builtin_nontemporal_store(o2, reinterpret_cast<vf4*>(ob + (size_t)2 * HH * WW));
    }
}

extern "C" void kernel_launch(void* const* d_in, const int* in_sizes, int n_in,
                              void* d_out, int out_size, void* d_ws, size_t ws_size,
                              hipStream_t stream) {
    const float* grid  = (const float*)d_in[0];
    const float* guide = (const float*)d_in[1];
    const float* image = (const float*)d_in[2];
    float* out = (float*)d_out;

    const int nblocks = BB * HH / ROWS;  // 2048 blocks, 2 rows each
    slice_apply<<<nblocks, 256, 0, stream>>>(grid, guide, image, out);
}

// Round 6
// 119.842 us; speedup vs baseline: 1.1097x; 1.0030x over previous
//
#include <hip/hip_runtime.h>

// Problem constants (from reference setup_inputs)
#define BB 4
#define CC 12
#define DD 8
#define HG 16
#define WG 16
#define HH 1024
#define WW 1024

// Native 4-float vector (clang ext vector) — legal operand for
// __builtin_nontemporal_load/store.
typedef float vf4 __attribute__((ext_vector_type(4)));

// LDS slab layout per row: S[x*XSTRIDE + z*CC + c], y-interpolation pre-folded.
// XSTRIDE = 8*12 + 8 pad floats = 104 -> cells stay 16B-aligned and
// bank = (8x + 12z + c) % 32 spreads the guide-random z across banks.
#define XSTRIDE 104
#define ROWS 2   // grid = 2048 blocks. Even h0 never straddles an fy band.
#define NSTG 6   // CC*DD*WG / 256 staging cells per thread

// (256,4): cap VGPR at 128 to guarantee 4 waves/SIMD (16 waves/CU).
// Live-set audit ~106 regs -> fits without the round-4 (256,6) collapse
// (that forced <=84 and the allocator serialized everything to VGPR=40).
// Unbounded, the allocator tends to settle >128 -> only 3 waves/SIMD,
// which matches the observed ~64% LDS-pipe duty.
__global__ __launch_bounds__(256, 4) void slice_apply(
    const float* __restrict__ grid,   // [B,C,D,HG,WG]
    const float* __restrict__ guide,  // [B,H,W]
    const float* __restrict__ img,    // [B,3,H,W]
    float* __restrict__ out)          // [B,3,H,W]
{
    __shared__ float S[ROWS * WG * XSTRIDE];  // 2 * 6656 B = 13312 B

    const int blk = blockIdx.x;
    const int b  = blk >> 9;                 // HH/ROWS = 512 row-groups per batch
    const int h0 = (blk & 511) * ROWS;

    // y-cell pair shared by all ROWS rows of this block
    const float gy0 = (h0 + 0.5f) * ((float)HG / (float)HH);
    const float fy  = floorf(gy0 - 0.5f);
    const int   iy0 = max(0, min(HG - 1, (int)fy));
    const int   iy1 = max(0, min(HG - 1, (int)fy + 1));

    float wy1r[ROWS];
    #pragma unroll
    for (int r = 0; r < ROWS; ++r) {
        const float gy = (h0 + r + 0.5f) * ((float)HG / (float)HH);
        wy1r[r] = gy - 0.5f - fy;           // ty in [0,1)
    }

    // ---- Issue the block's 12 grid loads first (oldest in the vmem queue;
    // L2-resident after the first touch). Flat index ordered (c,z,x) so
    // consecutive threads read consecutive x (coalesced 64B segments).
    float v0[NSTG], v1[NSTG];
    int   so[NSTG];
    #pragma unroll
    for (int t = 0; t < NSTG; ++t) {
        const int j = (int)threadIdx.x + t * 256;
        const int x = j & 15;
        const int z = (j >> 4) & 7;
        const int c = j >> 7;
        const size_t base = ((size_t)(b * CC + c) * DD + z) * (HG * WG);
        v0[t] = grid[base + iy0 * WG + x];
        v1[t] = grid[base + iy1 * WG + x];
        so[t] = x * XSTRIDE + z * CC + c;
    }

    // ---- Issue all 8 guide/image vector loads for the 2 rows BEFORE the
    // barrier (the barrier's fence semantics stop the compiler from hoisting
    // them itself). Their latency drains under the staging fold + barrier
    // wait; the compute phase then waits only on LDS.
    const int w0 = (int)threadIdx.x * 4;
    vf4 g4[ROWS], i0[ROWS], i1[ROWS], i2[ROWS];
    #pragma unroll
    for (int r = 0; r < ROWS; ++r) {
        const size_t pix = ((size_t)b * HH + (h0 + r)) * WW + w0;
        g4[r] = *reinterpret_cast<const vf4*>(guide + pix);
        const float* ib = img + (((size_t)b * 3) * HH + (h0 + r)) * WW + w0;
        i0[r] = __builtin_nontemporal_load(reinterpret_cast<const vf4*>(ib));
        i1[r] = __builtin_nontemporal_load(reinterpret_cast<const vf4*>(ib + (size_t)HH * WW));
        i2[r] = __builtin_nontemporal_load(reinterpret_cast<const vf4*>(ib + (size_t)2 * HH * WW));
    }

    // ---- Fold the y-lerp into ROWS per-row slabs (waits only on the 12 grid
    // loads; the 8 pixel loads stay in flight across the barrier).
    #pragma unroll
    for (int t = 0; t < NSTG; ++t) {
        const float d = v1[t] - v0[t];
        #pragma unroll
        for (int r = 0; r < ROWS; ++r) {
            S[r * (WG * XSTRIDE) + so[t]] = v0[t] + wy1r[r] * d;
        }
    }
    __syncthreads();

    // x cell pair is uniform across the 4 pixels of this thread
    const float scale = (float)WG / (float)WW;       // 1/64
    const float gx0 = (w0 + 0.5f) * scale;
    const float fx  = floorf(gx0 - 0.5f);
    const float tx0 = gx0 - 0.5f - fx;
    const int   ix0 = max(0, min(WG - 1, (int)fx));
    const int   ix1 = max(0, min(WG - 1, (int)fx + 1));

    #pragma unroll
    for (int r = 0; r < ROWS; ++r) {
        const int h = h0 + r;
        const float* Sr  = S + r * (WG * XSTRIDE);
        const float* Sx0 = Sr + ix0 * XSTRIDE;
        const float* Sx1 = Sr + ix1 * XSTRIDE;

        vf4 o0, o1, o2;

        #pragma unroll
        for (int p = 0; p < 4; ++p) {
            const float tx  = tx0 + (float)p * scale;
            const float wx0 = 1.0f - tx, wx1 = tx;

            const float gv = g4[r][p];
            const float gz  = gv * (float)DD;
            const float fz  = floorf(gz - 0.5f);
            const float tz  = gz - 0.5f - fz;
            const int   iz0 = max(0, min(DD - 1, (int)fz));
            const int   iz1 = max(0, min(DD - 1, (int)fz + 1));
            const float wz0 = 1.0f - tz, wz1 = tz;

            const float w00 = wz0 * wx0, w01 = wz0 * wx1;
            const float w10 = wz1 * wx0, w11 = wz1 * wx1;

            float acc[12];
            #pragma unroll
            for (int k = 0; k < 12; ++k) acc[k] = 0.0f;

            auto accum = [&](const float* P, float w) {
                const vf4 a = *reinterpret_cast<const vf4*>(P);
                const vf4 e = *reinterpret_cast<const vf4*>(P + 4);
                const vf4 f = *reinterpret_cast<const vf4*>(P + 8);
                #pragma unroll
                for (int k = 0; k < 4; ++k) {
                    acc[k]     += w * a[k];
                    acc[4 + k] += w * e[k];
                    acc[8 + k] += w * f[k];
                }
            };
            accum(Sx0 + iz0 * CC, w00);
            accum(Sx1 + iz0 * CC, w01);
            accum(Sx0 + iz1 * CC, w10);
            accum(Sx1 + iz1 * CC, w11);

            const float im0 = i0[r][p];
            const float im1 = i1[r][p];
            const float im2 = i2[r][p];

            o0[p] = acc[0] * im0 + acc[1] * im1 + acc[2]  * im2 + acc[3];
            o1[p] = acc[4] * im0 + acc[5] * im1 + acc[6]  * im2 + acc[7];
            o2[p] = acc[8] * im0 + acc[9] * im1 + acc[10] * im2 + acc[11];
        }

        float* ob = out + (((size_t)b * 3) * HH + h) * WW + w0;
        __builtin_nontemporal_store(o0, reinterpret_cast<vf4*>(ob));
        __builtin_nontemporal_store(o1, reinterpret_cast<vf4*>(ob + (size_t)HH * WW));
        __builtin_nontemporal_store(o2, reinterpret_cast<vf4*>(ob + (size_t)2 * HH * WW));
    }
}

extern "C" void kernel_launch(void* const* d_in, const int* in_sizes, int n_in,
                              void* d_out, int out_size, void* d_ws, size_t ws_size,
                              hipStream_t stream) {
    const float* grid  = (const float*)d_in[0];
    const float* guide = (const float*)d_in[1];
    const float* image = (const float*)d_in[2];
    float* out = (float*)d_out;

    const int nblocks = BB * HH / ROWS;  // 2048 blocks, 2 rows each
    slice_apply<<<nblocks, 256, 0, stream>>>(grid, guide, image, out);
}

// Round 7
// 119.735 us; speedup vs baseline: 1.1107x; 1.0009x over previous
//
#include <hip/hip_runtime.h>

// Problem constants (from reference setup_inputs)
#define BB 4
#define CC 12
#define DD 8
#define HG 16
#define WG 16
#define HH 1024
#define WW 1024

// Native 4-float vector (clang ext vector) — legal operand for
// __builtin_nontemporal_load/store.
typedef float vf4 __attribute__((ext_vector_type(4)));
typedef _Float16 h4 __attribute__((ext_vector_type(4)));  // 8B LDS read unit
typedef _Float16 h2 __attribute__((ext_vector_type(2)));  // 4B LDS write unit

// f16 LDS slab (round-7 change): the LDS pipe is the dominant serial term
// (23 of ~36 us: 786K wave ds_read_b128 at ~12+6-conflict cyc). Halving the
// element size halves both the data cycles (b64 = 4-cyc floor vs b128 = 8)
// and the conflict cycles. Unpack is free via v_fma_mix_f32 (clang fuses
// (float)h * w + acc). Grid ~N(0,1) -> f16 RTN adds ~2.4e-4 rel on coeffs.
//
// Layout per row: S[x*XSTRH + z*12 + c] (halfs), XSTRH = 96 data + 8 pad
// = 104 halfs = 208 B -> x rotates banks by 52 quads ≡ 20 (mod 32): 8
// distinct 4-aligned starts; z*6 quads also 8 distinct -> spread preserved.
// Cells are 24 B, 8B-aligned -> 3x ds_read_b64 per cell.
#define XSTRH 104
#define ROWS 2   // grid = 2048 blocks. Even h0 never straddles an fy band.
#define NSTG 3   // channel-PAIR staging stages: 768 pair-cells / 256 threads

__global__ __launch_bounds__(256, 4) void slice_apply(
    const float* __restrict__ grid,   // [B,C,D,HG,WG]
    const float* __restrict__ guide,  // [B,H,W]
    const float* __restrict__ img,    // [B,3,H,W]
    float* __restrict__ out)          // [B,3,H,W]
{
    __shared__ _Float16 S[ROWS * WG * XSTRH];  // 2*16*104*2 B = 6656 B

    const int blk = blockIdx.x;
    const int b  = blk >> 9;                 // HH/ROWS = 512 row-groups per batch
    const int h0 = (blk & 511) * ROWS;

    // y-cell pair shared by all ROWS rows of this block
    const float gy0 = (h0 + 0.5f) * ((float)HG / (float)HH);
    const float fy  = floorf(gy0 - 0.5f);
    const int   iy0 = max(0, min(HG - 1, (int)fy));
    const int   iy1 = max(0, min(HG - 1, (int)fy + 1));

    float wy1r[ROWS];
    #pragma unroll
    for (int r = 0; r < ROWS; ++r) {
        const float gy = (h0 + r + 0.5f) * ((float)HG / (float)HH);
        wy1r[r] = gy - 0.5f - fy;           // ty in [0,1)
    }

    // ---- Issue the block's 12 grid loads first (channel-pair layout:
    // j in [0,768): x = j&15, z = (j>>4)&7, pair = j>>7; each j loads the
    // two y-slices for channels 2p and 2p+1). Consecutive threads read
    // consecutive x (coalesced 64B segments), L2-resident.
    float a0[NSTG], a1[NSTG], c0v[NSTG], c1v[NSTG];
    int   so[NSTG];
    #pragma unroll
    for (int t = 0; t < NSTG; ++t) {
        const int j = (int)threadIdx.x + t * 256;
        const int x = j & 15;
        const int z = (j >> 4) & 7;
        const int pr = j >> 7;              // 0..5
        const size_t base0 = ((size_t)(b * CC + 2 * pr) * DD + z) * (HG * WG);
        const size_t base1 = ((size_t)(b * CC + 2 * pr + 1) * DD + z) * (HG * WG);
        a0[t] = grid[base0 + iy0 * WG + x];
        a1[t] = grid[base0 + iy1 * WG + x];
        c0v[t] = grid[base1 + iy0 * WG + x];
        c1v[t] = grid[base1 + iy1 * WG + x];
        so[t] = x * XSTRH + z * 12 + 2 * pr;
    }

    // ---- Issue all 8 guide/image vector loads BEFORE the barrier (the
    // barrier fence stops the compiler hoisting them itself). Latency
    // drains under the staging fold + barrier wait.
    const int w0 = (int)threadIdx.x * 4;
    vf4 g4[ROWS], i0[ROWS], i1[ROWS], i2[ROWS];
    #pragma unroll
    for (int r = 0; r < ROWS; ++r) {
        const size_t pix = ((size_t)b * HH + (h0 + r)) * WW + w0;
        g4[r] = *reinterpret_cast<const vf4*>(guide + pix);
        const float* ib = img + (((size_t)b * 3) * HH + (h0 + r)) * WW + w0;
        i0[r] = __builtin_nontemporal_load(reinterpret_cast<const vf4*>(ib));
        i1[r] = __builtin_nontemporal_load(reinterpret_cast<const vf4*>(ib + (size_t)HH * WW));
        i2[r] = __builtin_nontemporal_load(reinterpret_cast<const vf4*>(ib + (size_t)2 * HH * WW));
    }

    // ---- Fold the y-lerp in f32, convert once (RTN), store channel-pairs
    // as one ds_write_b32 each (byte addr = 4*(x*52 + z*6 + pr), 4-aligned).
    #pragma unroll
    for (int t = 0; t < NSTG; ++t) {
        const float d0 = a1[t] - a0[t];
        const float d1 = c1v[t] - c0v[t];
        #pragma unroll
        for (int r = 0; r < ROWS; ++r) {
            const float f0 = a0[t] + wy1r[r] * d0;
            const float f1 = c0v[t] + wy1r[r] * d1;
            h2 v; v[0] = (_Float16)f0; v[1] = (_Float16)f1;
            *reinterpret_cast<h2*>(&S[r * (WG * XSTRH) + so[t]]) = v;
        }
    }
    __syncthreads();

    // x cell pair is uniform across the 4 pixels of this thread
    const float scale = (float)WG / (float)WW;       // 1/64
    const float gx0 = (w0 + 0.5f) * scale;
    const float fx  = floorf(gx0 - 0.5f);
    const float tx0 = gx0 - 0.5f - fx;
    const int   ix0 = max(0, min(WG - 1, (int)fx));
    const int   ix1 = max(0, min(WG - 1, (int)fx + 1));

    #pragma unroll
    for (int r = 0; r < ROWS; ++r) {
        const int h = h0 + r;
        const _Float16* Sr  = S + r * (WG * XSTRH);
        const _Float16* Sx0 = Sr + ix0 * XSTRH;
        const _Float16* Sx1 = Sr + ix1 * XSTRH;

        vf4 o0, o1, o2;

        #pragma unroll
        for (int p = 0; p < 4; ++p) {
            const float tx  = tx0 + (float)p * scale;
            const float wx0 = 1.0f - tx, wx1 = tx;

            const float gv = g4[r][p];
            const float gz  = gv * (float)DD;
            const float fz  = floorf(gz - 0.5f);
            const float tz  = gz - 0.5f - fz;
            const int   iz0 = max(0, min(DD - 1, (int)fz));
            const int   iz1 = max(0, min(DD - 1, (int)fz + 1));
            const float wz0 = 1.0f - tz, wz1 = tz;

            const float w00 = wz0 * wx0, w01 = wz0 * wx1;
            const float w10 = wz1 * wx0, w11 = wz1 * wx1;

            float acc[12];
            #pragma unroll
            for (int k = 0; k < 12; ++k) acc[k] = 0.0f;

            // 3x ds_read_b64 per cell; (float)h * w + acc fuses to
            // v_fma_mix_f32 (no explicit cvt chain).
            auto accum = [&](const _Float16* P, float w) {
                const h4 a = *reinterpret_cast<const h4*>(P);
                const h4 e = *reinterpret_cast<const h4*>(P + 4);
                const h4 f = *reinterpret_cast<const h4*>(P + 8);
                #pragma unroll
                for (int k = 0; k < 4; ++k) {
                    acc[k]     += w * (float)a[k];
                    acc[4 + k] += w * (float)e[k];
                    acc[8 + k] += w * (float)f[k];
                }
            };
            accum(Sx0 + iz0 * 12, w00);
            accum(Sx1 + iz0 * 12, w01);
            accum(Sx0 + iz1 * 12, w10);
            accum(Sx1 + iz1 * 12, w11);

            const float im0 = i0[r][p];
            const float im1 = i1[r][p];
            const float im2 = i2[r][p];

            o0[p] = acc[0] * im0 + acc[1] * im1 + acc[2]  * im2 + acc[3];
            o1[p] = acc[4] * im0 + acc[5] * im1 + acc[6]  * im2 + acc[7];
            o2[p] = acc[8] * im0 + acc[9] * im1 + acc[10] * im2 + acc[11];
        }

        float* ob = out + (((size_t)b * 3) * HH + h) * WW + w0;
        __builtin_nontemporal_store(o0, reinterpret_cast<vf4*>(ob));
        __builtin_nontemporal_store(o1, reinterpret_cast<vf4*>(ob + (size_t)HH * WW));
        __builtin_nontemporal_store(o2, reinterpret_cast<vf4*>(ob + (size_t)2 * HH * WW));
    }
}

extern "C" void kernel_launch(void* const* d_in, const int* in_sizes, int n_in,
                              void* d_out, int out_size, void* d_ws, size_t ws_size,
                              hipStream_t stream) {
    const float* grid  = (const float*)d_in[0];
    const float* guide = (const float*)d_in[1];
    const float* image = (const float*)d_in[2];
    float* out = (float*)d_out;

    const int nblocks = BB * HH / ROWS;  // 2048 blocks, 2 rows each
    slice_apply<<<nblocks, 256, 0, stream>>>(grid, guide, image, out);
}

// Round 8
// 117.307 us; speedup vs baseline: 1.1337x; 1.0207x over previous
//
#include <hip/hip_runtime.h>

// Problem constants (from reference setup_inputs)
#define BB 4
#define CC 12
#define DD 8
#define HG 16
#define WG 16
#define HH 1024
#define WW 1024

// Native 4-float vector (clang ext vector).
typedef float vf4 __attribute__((ext_vector_type(4)));
typedef _Float16 h4 __attribute__((ext_vector_type(4)));  // 8B LDS read unit
typedef _Float16 h2 __attribute__((ext_vector_type(2)));  // 4B LDS write unit

// Round-8 single-variable change: PLAIN stores instead of
// __builtin_nontemporal_store. Rationale: kernel moves ~111 MB at only
// 3.0 TB/s while fills on the same chip hit 6.3+; WRITE_SIZE shows 70.3 MB
// for a 50.3 MB output (+40% amplification), and the NT-store L2 bypass is
// the only nonstandard element of the write path. Plain stores use the
// write-back L2 (full-line, lazy drain, overlaps with reads).
//
// f16 slab layout per row: S[x*XSTRH + z*12 + c] (halfs), XSTRH = 96 data
// + 8 pad = 104 halfs = 208 B. Cells are 24 B, 8B-aligned -> 3x ds_read_b64.
#define XSTRH 104
#define ROWS 2   // grid = 2048 blocks. Even h0 never straddles an fy band.
#define NSTG 3   // channel-PAIR staging stages: 768 pair-cells / 256 threads

__global__ __launch_bounds__(256, 4) void slice_apply(
    const float* __restrict__ grid,   // [B,C,D,HG,WG]
    const float* __restrict__ guide,  // [B,H,W]
    const float* __restrict__ img,    // [B,3,H,W]
    float* __restrict__ out)          // [B,3,H,W]
{
    __shared__ _Float16 S[ROWS * WG * XSTRH];  // 6656 B

    const int blk = blockIdx.x;
    const int b  = blk >> 9;                 // HH/ROWS = 512 row-groups per batch
    const int h0 = (blk & 511) * ROWS;

    // y-cell pair shared by all ROWS rows of this block
    const float gy0 = (h0 + 0.5f) * ((float)HG / (float)HH);
    const float fy  = floorf(gy0 - 0.5f);
    const int   iy0 = max(0, min(HG - 1, (int)fy));
    const int   iy1 = max(0, min(HG - 1, (int)fy + 1));

    float wy1r[ROWS];
    #pragma unroll
    for (int r = 0; r < ROWS; ++r) {
        const float gy = (h0 + r + 0.5f) * ((float)HG / (float)HH);
        wy1r[r] = gy - 0.5f - fy;           // ty in [0,1)
    }

    // ---- Issue the block's 12 grid loads first (channel-pair layout).
    float a0[NSTG], a1[NSTG], c0v[NSTG], c1v[NSTG];
    int   so[NSTG];
    #pragma unroll
    for (int t = 0; t < NSTG; ++t) {
        const int j = (int)threadIdx.x + t * 256;
        const int x = j & 15;
        const int z = (j >> 4) & 7;
        const int pr = j >> 7;              // 0..5
        const size_t base0 = ((size_t)(b * CC + 2 * pr) * DD + z) * (HG * WG);
        const size_t base1 = ((size_t)(b * CC + 2 * pr + 1) * DD + z) * (HG * WG);
        a0[t] = grid[base0 + iy0 * WG + x];
        a1[t] = grid[base0 + iy1 * WG + x];
        c0v[t] = grid[base1 + iy0 * WG + x];
        c1v[t] = grid[base1 + iy1 * WG + x];
        so[t] = x * XSTRH + z * 12 + 2 * pr;
    }

    // ---- Issue all 8 guide/image vector loads BEFORE the barrier (the
    // barrier fence stops the compiler hoisting them itself).
    const int w0 = (int)threadIdx.x * 4;
    vf4 g4[ROWS], i0[ROWS], i1[ROWS], i2[ROWS];
    #pragma unroll
    for (int r = 0; r < ROWS; ++r) {
        const size_t pix = ((size_t)b * HH + (h0 + r)) * WW + w0;
        g4[r] = *reinterpret_cast<const vf4*>(guide + pix);
        const float* ib = img + (((size_t)b * 3) * HH + (h0 + r)) * WW + w0;
        i0[r] = __builtin_nontemporal_load(reinterpret_cast<const vf4*>(ib));
        i1[r] = __builtin_nontemporal_load(reinterpret_cast<const vf4*>(ib + (size_t)HH * WW));
        i2[r] = __builtin_nontemporal_load(reinterpret_cast<const vf4*>(ib + (size_t)2 * HH * WW));
    }

    // ---- Fold the y-lerp in f32, convert once (RTN), store channel-pairs
    // as one ds_write_b32 each.
    #pragma unroll
    for (int t = 0; t < NSTG; ++t) {
        const float d0 = a1[t] - a0[t];
        const float d1 = c1v[t] - c0v[t];
        #pragma unroll
        for (int r = 0; r < ROWS; ++r) {
            const float f0 = a0[t] + wy1r[r] * d0;
            const float f1 = c0v[t] + wy1r[r] * d1;
            h2 v; v[0] = (_Float16)f0; v[1] = (_Float16)f1;
            *reinterpret_cast<h2*>(&S[r * (WG * XSTRH) + so[t]]) = v;
        }
    }
    __syncthreads();

    // x cell pair is uniform across the 4 pixels of this thread
    const float scale = (float)WG / (float)WW;       // 1/64
    const float gx0 = (w0 + 0.5f) * scale;
    const float fx  = floorf(gx0 - 0.5f);
    const float tx0 = gx0 - 0.5f - fx;
    const int   ix0 = max(0, min(WG - 1, (int)fx));
    const int   ix1 = max(0, min(WG - 1, (int)fx + 1));

    #pragma unroll
    for (int r = 0; r < ROWS; ++r) {
        const int h = h0 + r;
        const _Float16* Sr  = S + r * (WG * XSTRH);
        const _Float16* Sx0 = Sr + ix0 * XSTRH;
        const _Float16* Sx1 = Sr + ix1 * XSTRH;

        vf4 o0, o1, o2;

        #pragma unroll
        for (int p = 0; p < 4; ++p) {
            const float tx  = tx0 + (float)p * scale;
            const float wx0 = 1.0f - tx, wx1 = tx;

            const float gv = g4[r][p];
            const float gz  = gv * (float)DD;
            const float fz  = floorf(gz - 0.5f);
            const float tz  = gz - 0.5f - fz;
            const int   iz0 = max(0, min(DD - 1, (int)fz));
            const int   iz1 = max(0, min(DD - 1, (int)fz + 1));
            const float wz0 = 1.0f - tz, wz1 = tz;

            const float w00 = wz0 * wx0, w01 = wz0 * wx1;
            const float w10 = wz1 * wx0, w11 = wz1 * wx1;

            float acc[12];
            #pragma unroll
            for (int k = 0; k < 12; ++k) acc[k] = 0.0f;

            // 3x ds_read_b64 per cell; (float)h * w + acc fuses to
            // v_fma_mix_f32.
            auto accum = [&](const _Float16* P, float w) {
                const h4 a = *reinterpret_cast<const h4*>(P);
                const h4 e = *reinterpret_cast<const h4*>(P + 4);
                const h4 f = *reinterpret_cast<const h4*>(P + 8);
                #pragma unroll
                for (int k = 0; k < 4; ++k) {
                    acc[k]     += w * (float)a[k];
                    acc[4 + k] += w * (float)e[k];
                    acc[8 + k] += w * (float)f[k];
                }
            };
            accum(Sx0 + iz0 * 12, w00);
            accum(Sx1 + iz0 * 12, w01);
            accum(Sx0 + iz1 * 12, w10);
            accum(Sx1 + iz1 * 12, w11);

            const float im0 = i0[r][p];
            const float im1 = i1[r][p];
            const float im2 = i2[r][p];

            o0[p] = acc[0] * im0 + acc[1] * im1 + acc[2]  * im2 + acc[3];
            o1[p] = acc[4] * im0 + acc[5] * im1 + acc[6]  * im2 + acc[7];
            o2[p] = acc[8] * im0 + acc[9] * im1 + acc[10] * im2 + acc[11];
        }

        // PLAIN stores (round-8 change): route writes through the
        // write-back L2 instead of the NT bypass.
        float* ob = out + (((size_t)b * 3) * HH + h) * WW + w0;
        *reinterpret_cast<vf4*>(ob) = o0;
        *reinterpret_cast<vf4*>(ob + (size_t)HH * WW) = o1;
        *reinterpret_cast<vf4*>(ob + (size_t)2 * HH * WW) = o2;
    }
}

extern "C" void kernel_launch(void* const* d_in, const int* in_sizes, int n_in,
                              void* d_out, int out_size, void* d_ws, size_t ws_size,
                              hipStream_t stream) {
    const float* grid  = (const float*)d_in[0];
    const float* guide = (const float*)d_in[1];
    const float* image = (const float*)d_in[2];
    float* out = (float*)d_out;

    const int nblocks = BB * HH / ROWS;  // 2048 blocks, 2 rows each
    slice_apply<<<nblocks, 256, 0, stream>>>(grid, guide, image, out);
}